// Round 10
// baseline (175.553 us; speedup 1.0000x reference)
//
#include <hip/hip_runtime.h>
#include <stdint.h>

// Problem constants (B,C,H,W = 8,256,48,48)
#define NB  8
#define NC  256
#define NCR 32
#define NSP 2304  // N = H*W
#define LOG2E 1.44269504088896340736f

typedef __attribute__((ext_vector_type(8))) short short8;   // 8 x bf16 (4 VGPRs)
typedef __attribute__((ext_vector_type(4))) float f32x4;    // MFMA C/D frag
typedef __attribute__((ext_vector_type(4))) unsigned short us4;
typedef __attribute__((ext_vector_type(2))) unsigned int u32x2;

__device__ __forceinline__ unsigned short f2bf(float f) {
  union { float f; unsigned u; } a; a.f = f;
  unsigned r = (a.u + 0x7FFFu + ((a.u >> 16) & 1u)) >> 16;  // RNE
  return (unsigned short)r;
}

__device__ __forceinline__ float fexp2(float x) {
#if __has_builtin(__builtin_amdgcn_exp2f)
  return __builtin_amdgcn_exp2f(x);
#else
  return __exp2f(x);
#endif
}

// pack 4 fp32 -> 4 bf16 (RNE) as two dwords
__device__ __forceinline__ u32x2 pack4bf(float a, float b, float c, float d) {
  u32x2 r;
#if __has_builtin(__builtin_amdgcn_cvt_pk_bf16_f32)
  typedef __attribute__((ext_vector_type(2))) __bf16 bf2;
  union { bf2 v; unsigned u; } lo, hi;
  lo.v = __builtin_amdgcn_cvt_pk_bf16_f32(a, b);
  hi.v = __builtin_amdgcn_cvt_pk_bf16_f32(c, d);
  r[0] = lo.u; r[1] = hi.u;
#else
  r[0] = (unsigned)f2bf(a) | ((unsigned)f2bf(b) << 16);
  r[1] = (unsigned)f2bf(c) | ((unsigned)f2bf(d) << 16);
#endif
  return r;
}

typedef __attribute__((address_space(1))) const void* gvoidp;
typedef __attribute__((address_space(3))) void* lvoidp;
#define GLOADLDS16(g, l) __builtin_amdgcn_global_load_lds((gvoidp)(g), (lvoidp)(l), 16, 0, 0)

// ---------------------------------------------------------------------------
// Kernel 1 (fused transpose + QKV projection) — UNCHANGED (proven).
// Q pre-scaled by log2(e) so softmax uses bare v_exp_f32.
__global__ __launch_bounds__(256) void k_proj(const float* __restrict__ x,
    const float* __restrict__ w1, const float* __restrict__ b1,
    const float* __restrict__ w2, const float* __restrict__ b2,
    const float* __restrict__ w3, const float* __restrict__ b3,
    unsigned short* __restrict__ Q, unsigned short* __restrict__ K,
    unsigned short* __restrict__ V) {
  __shared__ unsigned short xs[32][264];  // [n][c], +8 pad
  const int n0 = blockIdx.x * 32, b = blockIdx.y;
  const int t = threadIdx.x, lane = t & 63, wave = t >> 6;
  const int col = lane & 15, quad = lane >> 4;
  const float* xb = x + (size_t)b * NC * NSP;
#pragma unroll
  for (int p = 0; p < 8; ++p) {
    const int crow = (t >> 3) + p * 32;     // 0..255
    const int n4 = (t & 7) * 4;             // 0..28
    float4 v = *(const float4*)(xb + (size_t)crow * NSP + n0 + n4);
    xs[n4 + 0][crow] = f2bf(v.x);
    xs[n4 + 1][crow] = f2bf(v.y);
    xs[n4 + 2][crow] = f2bf(v.z);
    xs[n4 + 3][crow] = f2bf(v.w);
  }
  __syncthreads();
  const f32x4 zero4 = {0.f, 0.f, 0.f, 0.f};
  f32x4 acc[5][2];
#pragma unroll
  for (int i = 0; i < 5; ++i)
#pragma unroll
    for (int j = 0; j < 2; ++j) acc[i][j] = zero4;

  for (int kc = 0; kc < 8; ++kc) {
    short8 bf[2];
#pragma unroll
    for (int nt = 0; nt < 2; ++nt)
      bf[nt] = *(const short8*)&xs[nt * 16 + col][kc * 32 + quad * 8];
#pragma unroll
    for (int ml = 0; ml < 5; ++ml) {
      const int m0 = (wave * 5 + ml) * 16;
      const float* wbase; int roff;
      if (m0 < 32)      { wbase = w1; roff = m0; }
      else if (m0 < 64) { wbase = w2; roff = m0 - 32; }
      else              { wbase = w3; roff = m0 - 64; }
      const float* wp = wbase + (size_t)(roff + col) * NC + kc * 32 + quad * 8;
      float4 f0 = *(const float4*)wp;
      float4 f1 = *(const float4*)(wp + 4);
      short8 af;
      af[0] = f2bf(f0.x); af[1] = f2bf(f0.y); af[2] = f2bf(f0.z); af[3] = f2bf(f0.w);
      af[4] = f2bf(f1.x); af[5] = f2bf(f1.y); af[6] = f2bf(f1.z); af[7] = f2bf(f1.w);
#pragma unroll
      for (int nt = 0; nt < 2; ++nt)
        acc[ml][nt] = __builtin_amdgcn_mfma_f32_16x16x32_bf16(af, bf[nt], acc[ml][nt], 0, 0, 0);
    }
  }
#pragma unroll
  for (int ml = 0; ml < 5; ++ml) {
    const int m0 = (wave * 5 + ml) * 16;
    const float* bias;
    if (m0 < 32)      bias = b1 + m0;
    else if (m0 < 64) bias = b2 + (m0 - 32);
    else              bias = b3 + (m0 - 64);
    float bv[4];
#pragma unroll
    for (int r = 0; r < 4; ++r) bv[r] = bias[quad * 4 + r];
    if (m0 < 64) {  // Q or K : [b][n][32]
      unsigned short* dst = (m0 < 32) ? Q : K;
      const float scl = (m0 < 32) ? LOG2E : 1.0f;  // fold log2e into Q
      const int d0 = (m0 & 31) + quad * 4;
#pragma unroll
      for (int nt = 0; nt < 2; ++nt) {
        const int n = n0 + nt * 16 + col;
        us4 pk;
#pragma unroll
        for (int r = 0; r < 4; ++r) pk[r] = f2bf((acc[ml][nt][r] + bv[r]) * scl);
        *(us4*)(dst + ((size_t)b * NSP + n) * NCR + d0) = pk;
      }
    } else {        // V : [b][c][n]
      const int cbase = m0 - 64 + quad * 4;
#pragma unroll
      for (int nt = 0; nt < 2; ++nt) {
        const int n = n0 + nt * 16 + col;
#pragma unroll
        for (int r = 0; r < 4; ++r)
          V[((size_t)b * NC + cbase + r) * NSP + n] = f2bf(acc[ml][nt][r] + bv[r]);
      }
    }
  }
}

// ---------------------------------------------------------------------------
// Kernel 2 (fused attention, SPLIT-J x2): block = 48 i (3 waves x 16) x 128 c
// x 1152 j-half. grid (48, 4, 8) = 1536 blocks, 4608 waves = 4.5/SIMD;
// LDS 24.1KB -> 6 blocks/CU co-resident (the occupancy unlock vs R9's 2.25).
// j-tile 32: Vs [buf][128 c][32 j] (64B rows, 16B-chunk XOR swizzle
// phys = logical ^ (c&3), 2 lanes/bank = free), Ps [wave][buf][16 i][40].
// 1-barrier pipeline: barrier -> kb(n+1) -> stage(n+1) -> PV(n) ->
// scores(n+1) (S^T via operand swap, bare v_exp_f32, packed 8B Ps writes).
// Writes RAW partial O (fp32) + partial l to ws; k_combine finishes.
__global__ __launch_bounds__(192) void k_attn(const unsigned short* __restrict__ Q,
    const unsigned short* __restrict__ K, const unsigned short* __restrict__ V,
    float* __restrict__ Op, float* __restrict__ lp) {
  __shared__ __align__(16) unsigned short smem[12032];  // 24064 B
  unsigned short* Vs = smem;          // [buf][128][32] : 2 x 4096 u16
  unsigned short* Ps = smem + 8192;   // [wave][buf][16][40] : 3 x 2 x 640 u16
  const int i0 = blockIdx.x * 48, b = blockIdx.z;
  const int ch = (blockIdx.y & 1) * 128, jh = blockIdx.y >> 1;
  const int jb = jh * 1152;
  const int t = threadIdx.x, lane = t & 63, wave = t >> 6;  // wave 0..2
  const int col = lane & 15, quad = lane >> 4;
  const int iw = i0 + wave * 16;
  const unsigned short* Qb = Q + (size_t)b * NSP * NCR;
  const unsigned short* Kb = K + (size_t)b * NSP * NCR;
  const unsigned short* Vb = V + (size_t)b * NC * NSP;
  unsigned short* PsW = Ps + wave * 1280;  // 2 bufs x 640

  const short8 qa = *(const short8*)(Qb + (size_t)(iw + col) * NCR + quad * 8);
  const f32x4 zero4 = {0.f, 0.f, 0.f, 0.f};
  f32x4 acc[8];
#pragma unroll
  for (int ct = 0; ct < 8; ++ct) acc[ct] = zero4;
  float rs = 0.f;  // partial row-sum for i = col (this lane's quad's j-subset)
  // staging map: call q covers c-rows q*16..+15 (16 rows x 4 chunks of 16B);
  // lane -> row r4 = lane>>2, phys chunk pc = lane&3 holds logical pc^(r4&3).
  const int r4 = lane >> 2, pc = lane & 3, jcs = pc ^ (r4 & 3);

  // ---- prologue: kb(0), stage(0) -> buf0, scores(0) -> Ps buf0
  short8 kb[2];
#pragma unroll
  for (int mt = 0; mt < 2; ++mt)
    kb[mt] = *(const short8*)(Kb + (size_t)(jb + mt * 16 + col) * NCR + quad * 8);
#pragma unroll
  for (int cix = 0; cix < 3; ++cix) {
    const int q = wave * 3 + cix;          // 0..8; q==8 skipped (wave-uniform)
    if (q < 8) {
      const unsigned short* g = Vb + (size_t)(ch + q * 16 + r4) * NSP + jb + jcs * 8;
      GLOADLDS16(g, Vs + q * 512);
    }
  }
#pragma unroll
  for (int mt = 0; mt < 2; ++mt) {
    f32x4 s = __builtin_amdgcn_mfma_f32_16x16x32_bf16(kb[mt], qa, zero4, 0, 0, 0);
    const float e0 = fexp2(s[0]), e1 = fexp2(s[1]), e2 = fexp2(s[2]), e3 = fexp2(s[3]);
    rs += (e0 + e1) + (e2 + e3);
    *(u32x2*)(PsW + col * 40 + mt * 16 + quad * 4) = pack4bf(e0, e1, e2, e3);
  }

  // ---- main loop: one barrier per iteration, 36 j-tiles of 32
  for (int kc = 0; kc < 36; ++kc) {
    __syncthreads();  // Vs(kc) staged (vmcnt drained), Ps(kc) written
    const int bufc = kc & 1, bufn = bufc ^ 1;
    const int j1 = jb + (kc + 1) * 32;
    const bool more = (kc + 1 < 36);
    if (more) {
      // kb(n+1) first (in-order vmcnt: retires before the staging loads)
#pragma unroll
      for (int mt = 0; mt < 2; ++mt)
        kb[mt] = *(const short8*)(Kb + (size_t)(j1 + mt * 16 + col) * NCR + quad * 8);
      // stage(n+1) -> Vs bufn
#pragma unroll
      for (int cix = 0; cix < 3; ++cix) {
        const int q = wave * 3 + cix;
        if (q < 8) {
          const unsigned short* g = Vb + (size_t)(ch + q * 16 + r4) * NSP + j1 + jcs * 8;
          GLOADLDS16(g, Vs + bufn * 4096 + q * 512);
        }
      }
    }
    // PV(kc): K=32, single kk
    const unsigned short* pwc = PsW + bufc * 640;
    const unsigned short* vsc = Vs + bufc * 4096;
    const short8 pa = *(const short8*)(pwc + col * 40 + quad * 8);
#pragma unroll
    for (int ct = 0; ct < 8; ++ct) {
      const short8 vbf = *(const short8*)(vsc + (ct * 16 + col) * 32 +
                                          ((quad ^ (col & 3)) * 8));
      acc[ct] = __builtin_amdgcn_mfma_f32_16x16x32_bf16(pa, vbf, acc[ct], 0, 0, 0);
    }
    if (more) {
      // scores(n+1) -> Ps bufn  (S^T: lane holds 4 j-contiguous elems of row col)
      unsigned short* pwn = PsW + bufn * 640;
#pragma unroll
      for (int mt = 0; mt < 2; ++mt) {
        f32x4 s = __builtin_amdgcn_mfma_f32_16x16x32_bf16(kb[mt], qa, zero4, 0, 0, 0);
        const float e0 = fexp2(s[0]), e1 = fexp2(s[1]), e2 = fexp2(s[2]), e3 = fexp2(s[3]);
        rs += (e0 + e1) + (e2 + e3);
        *(u32x2*)(pwn + col * 40 + mt * 16 + quad * 4) = pack4bf(e0, e1, e2, e3);
      }
    }
  }

  // ---- partial l for i = col (sum the 4 quads), written once per (i, jh)
  rs += __shfl_xor(rs, 16, 64);
  rs += __shfl_xor(rs, 32, 64);
  if (((blockIdx.y & 1) == 0) && quad == 0)
    lp[((size_t)jh * NB + b) * NSP + iw + col] = rs;

  // ---- partial O store (raw fp32 sums; scaling/feat in k_combine)
  float* Ob = Op + (((size_t)jh * NB + b) * NC + ch) * NSP;
#pragma unroll
  for (int ct = 0; ct < 8; ++ct)
    *(f32x4*)(Ob + (size_t)(ct * 16 + col) * NSP + iw + quad * 4) = acc[ct];
}

// ---------------------------------------------------------------------------
// Kernel 3: out = (O0+O1) * gamma/(l0+l1) + feat. Elementwise float4.
// grid 4608 x 256 threads (8*256*2304/4 float4s).
__global__ __launch_bounds__(256) void k_combine(const float* __restrict__ Op,
    const float* __restrict__ lp, const float* __restrict__ feat,
    const float* __restrict__ gamma, float* __restrict__ out) {
  const int tid = blockIdx.x * 256 + threadIdx.x;
  const int b = tid / (NC * NSP / 4);
  const int rem = tid - b * (NC * NSP / 4);
  const int c = rem / (NSP / 4);
  const int i4 = (rem - c * (NSP / 4)) * 4;
  const size_t a = ((size_t)b * NC + c) * NSP + i4;
  const float4 o0 = *(const float4*)(Op + a);
  const float4 o1 = *(const float4*)(Op + (size_t)NB * NC * NSP + a);
  const float4 l0 = *(const float4*)(lp + (size_t)b * NSP + i4);
  const float4 l1 = *(const float4*)(lp + (size_t)(NB + b) * NSP + i4);
  const float4 ft = *(const float4*)(feat + a);
  const float g = gamma[0];
  float4 o;
  o.x = (o0.x + o1.x) * (g / (l0.x + l1.x)) + ft.x;
  o.y = (o0.y + o1.y) * (g / (l0.y + l1.y)) + ft.y;
  o.z = (o0.z + o1.z) * (g / (l0.z + l1.z)) + ft.z;
  o.w = (o0.w + o1.w) * (g / (l0.w + l1.w)) + ft.w;
  *(float4*)(out + a) = o;
}

// ---------------------------------------------------------------------------
// Workspace layout (bytes), total 49,692,672 (~47.4 MB):
//   Q  : [0, 1179648)             bf16 [8][2304][32]  (pre-scaled by log2e)
//   K  : [1179648, 2359296)       bf16 [8][2304][32]
//   V  : [2359296, 11796480)      bf16 [8][256][2304]
//   Op : [11796480, 49545216)     fp32 [2 jh][8][256][2304] partial O
//   lp : [49545216, 49692672)     fp32 [2 jh][8][2304]      partial l
#define OFF_Q  0UL
#define OFF_K  1179648UL
#define OFF_V  2359296UL
#define OFF_OP 11796480UL
#define OFF_LP 49545216UL

extern "C" void kernel_launch(void* const* d_in, const int* in_sizes, int n_in,
                              void* d_out, int out_size, void* d_ws, size_t ws_size,
                              hipStream_t stream) {
  const float* feat  = (const float*)d_in[0];
  const float* w1    = (const float*)d_in[1];
  const float* b1    = (const float*)d_in[2];
  const float* w2    = (const float*)d_in[3];
  const float* b2    = (const float*)d_in[4];
  const float* w3    = (const float*)d_in[5];
  const float* b3    = (const float*)d_in[6];
  const float* gamma = (const float*)d_in[7];
  float* out = (float*)d_out;
  char* ws = (char*)d_ws;
  unsigned short* Q = (unsigned short*)(ws + OFF_Q);
  unsigned short* K = (unsigned short*)(ws + OFF_K);
  unsigned short* V = (unsigned short*)(ws + OFF_V);
  float* Op = (float*)(ws + OFF_OP);
  float* lp = (float*)(ws + OFF_LP);

  hipLaunchKernelGGL(k_proj, dim3(72, NB), dim3(256), 0, stream,
                     feat, w1, b1, w2, b2, w3, b3, Q, K, V);
  hipLaunchKernelGGL(k_attn, dim3(48, 4, NB), dim3(192), 0, stream,
                     Q, K, V, Op, lp);
  hipLaunchKernelGGL(k_combine, dim3(4608), dim3(256), 0, stream,
                     Op, lp, feat, gamma, out);
}